// Round 2
// baseline (2454.718 us; speedup 1.0000x reference)
//
#include <hip/hip_runtime.h>
#include <hip/hip_fp16.h>

// Problem constants
#define BB  64
#define CIN 256
#define HH  256
#define TT  512
#define G4  1024   // 4*H

typedef _Float16 half2_t __attribute__((ext_vector_type(2)));

__device__ __forceinline__ float dot2f(float wa, float hb, float acc) {
  half2_t a = __builtin_bit_cast(half2_t, wa);
  half2_t b = __builtin_bit_cast(half2_t, hb);
#if __has_builtin(__builtin_amdgcn_fdot2)
  return __builtin_amdgcn_fdot2(a, b, acc, false);
#else
  return acc + (float)a.x * (float)b.x + (float)a.y * (float)b.y;
#endif
}

__device__ __forceinline__ float dot8(float4 w, float4 h, float acc) {
  acc = dot2f(w.x, h.x, acc);
  acc = dot2f(w.y, h.y, acc);
  acc = dot2f(w.z, h.z, acc);
  acc = dot2f(w.w, h.w, acc);
  return acc;
}

__device__ __forceinline__ float fast_rcp(float x) { return __builtin_amdgcn_rcpf(x); }
__device__ __forceinline__ float fast_sig(float x) {
  return fast_rcp(1.0f + exp2f(-1.4426950408889634f * x));
}
__device__ __forceinline__ float fast_tanh(float x) {
  return 1.0f - 2.0f * fast_rcp(1.0f + exp2f(2.8853900817779268f * x));
}

// ---------------------------------------------------------------------------
// Kernel 0: W_hh (B,H,4H) fp32  ->  Wc (B,4H,H) f16  (per-gate-col contiguous)
// ---------------------------------------------------------------------------
__global__ __launch_bounds__(256) void transpose_whh(const float* __restrict__ W,
                                                     __half* __restrict__ Wc) {
  __shared__ __half tile[32][33];
  int b  = blockIdx.z;
  int j0 = blockIdx.x * 32;
  int k0 = blockIdx.y * 32;
  int tx = threadIdx.x;
  int ty = threadIdx.y;
  const float* Wb = W + (size_t)b * HH * G4;
#pragma unroll
  for (int r = 0; r < 32; r += 8)
    tile[ty + r][tx] = __float2half(Wb[(size_t)(k0 + ty + r) * G4 + j0 + tx]);
  __syncthreads();
  __half* out = Wc + (size_t)b * G4 * HH;
#pragma unroll
  for (int r = 0; r < 32; r += 8)
    out[(size_t)(j0 + ty + r) * HH + k0 + tx] = tile[tx][ty + r];
}

// ---------------------------------------------------------------------------
// Kernel 1: WX[b][t][j] = sum_i x[b][i][t] * W_ih[b][i][j] + b_h[b][j], f16 out.
// (unchanged this round; MFMA candidate next round)
// ---------------------------------------------------------------------------
__global__ __launch_bounds__(256) void gemm_wx(const float* __restrict__ X,
                                               const float* __restrict__ Wih,
                                               const float* __restrict__ bh,
                                               __half* __restrict__ WX) {
  __shared__ float As[16][64];
  __shared__ float Bs[16][64];
  int b  = blockIdx.z;
  int t0 = blockIdx.y * 64;
  int j0 = blockIdx.x * 64;
  int tid = threadIdx.x;
  int tx = tid & 15;
  int ty = tid >> 4;
  const float* Xb = X   + (size_t)b * CIN * TT;
  const float* Wb = Wih + (size_t)b * CIN * G4;
  float acc[4][4] = {};
  for (int i0 = 0; i0 < CIN; i0 += 16) {
#pragma unroll
    for (int q = 0; q < 4; ++q) {
      int lin = tid + q * 256;
      int k  = lin >> 6;
      int tt = lin & 63;
      As[k][tt] = Xb[(size_t)(i0 + k) * TT + t0 + tt];
      Bs[k][tt] = Wb[(size_t)(i0 + k) * G4 + j0 + tt];
    }
    __syncthreads();
#pragma unroll
    for (int k = 0; k < 16; ++k) {
      float4 av = *(const float4*)&As[k][ty * 4];
      float4 bv = *(const float4*)&Bs[k][tx * 4];
      float a[4] = {av.x, av.y, av.z, av.w};
      float c[4] = {bv.x, bv.y, bv.z, bv.w};
#pragma unroll
      for (int r = 0; r < 4; ++r)
#pragma unroll
        for (int cc = 0; cc < 4; ++cc)
          acc[r][cc] = fmaf(a[r], c[cc], acc[r][cc]);
    }
    __syncthreads();
  }
  const float* bias = bh + (size_t)b * G4;
  float bcol[4];
#pragma unroll
  for (int cc = 0; cc < 4; ++cc) bcol[cc] = bias[j0 + tx * 4 + cc];
#pragma unroll
  for (int r = 0; r < 4; ++r) {
    int t = t0 + ty * 4 + r;
    __half* dst = WX + ((size_t)b * TT + t) * G4 + j0 + tx * 4;
    __half2 p0 = __floats2half2_rn(acc[r][0] + bcol[0], acc[r][1] + bcol[1]);
    __half2 p1 = __floats2half2_rn(acc[r][2] + bcol[2], acc[r][3] + bcol[3]);
    float2 st;
    st.x = __builtin_bit_cast(float, p0);
    st.y = __builtin_bit_cast(float, p1);
    *(float2*)dst = st;
  }
}

// ---------------------------------------------------------------------------
// Kernel 2: recurrence, W_hh register-resident.
// 128 WGs x 512 threads: WG g -> batch (g&63), half (g>>6).
//   half 0 owns gate cols [0,512)   (i,f);  half 1 owns [512,1024) (g,o).
// Thread tid owns col j = half*512+tid: 256 f16 W column in 32 float4 VGPRs.
// Per step: dots from regs (h broadcast via LDS), exchange 512 f32 gates with
// peer WG through global memory + agent-scope release/acquire flags, both WGs
// redundantly compute the identical c/h update (bit-identical inputs).
// h_out buffered 16 steps in LDS -> full-64B-line stores (kills the 16x
// write amplification seen in R1: WRITE_SIZE 640 MB for a 32 MB output).
// ---------------------------------------------------------------------------
__global__ __launch_bounds__(512, 2) void lstm_rec2(const __half* __restrict__ Wc,
                                                    const __half* __restrict__ WX,
                                                    const float* __restrict__ h0,
                                                    const float* __restrict__ c0,
                                                    float* __restrict__ out,
                                                    float* __restrict__ xch,
                                                    int* __restrict__ flags) {
  __shared__ float4 h4[32];        // h as 256 f16
  __shared__ float  gown[512];     // own-half gates (f32)
  __shared__ float  hbuf[16][256]; // 16-step h staging (half 0 only)
  int g    = blockIdx.x;
  int b    = g & 63;
  int half = g >> 6;
  int tid  = threadIdx.x;
  int j    = half * 512 + tid;

  // W column -> 128 VGPRs
  const float4* wp = (const float4*)(Wc + ((size_t)b * G4 + j) * HH);
  float4 wreg[32];
#pragma unroll
  for (int m = 0; m < 32; ++m) wreg[m] = wp[m];

  float c_reg = 0.0f;
  if (tid < HH) {
    c_reg = c0[b * HH + tid];
    ((__half*)h4)[tid] = __float2half(h0[b * HH + tid]);
  }
  __syncthreads();

  float*       my_out  = xch + ((size_t)(b * 2 + half) * 2) * 512;
  const float* peer_in = xch + ((size_t)(b * 2 + (half ^ 1)) * 2) * 512;
  int* my_flag   = flags + (b * 2 + half);
  int* peer_flag = flags + (b * 2 + (half ^ 1));
  const __half* wxp = WX + (size_t)b * TT * G4 + j;
  float* outb = out + (size_t)b * HH * TT;

  for (int t = 0; t < TT; ++t) {
    float wx = __half2float(wxp[(size_t)t * G4]);   // issued early, L3-latency hidden by dots
    float a0 = 0.f, a1 = 0.f, a2 = 0.f, a3 = 0.f;
#pragma unroll
    for (int m = 0; m < 32; m += 4) {
      a0 = dot8(wreg[m + 0], h4[m + 0], a0);
      a1 = dot8(wreg[m + 1], h4[m + 1], a1);
      a2 = dot8(wreg[m + 2], h4[m + 2], a2);
      a3 = dot8(wreg[m + 3], h4[m + 3], a3);
    }
    float gate = fast_tanh((a0 + a1) + (a2 + a3) + wx);
    gown[tid] = gate;
    my_out[(t & 1) * 512 + tid] = gate;
    __syncthreads();   // LDS visible + vmcnt(0) drains the gate stores
    if (tid == 0) {
      __hip_atomic_store(my_flag, t + 1, __ATOMIC_RELEASE, __HIP_MEMORY_SCOPE_AGENT);
      while (__hip_atomic_load(peer_flag, __ATOMIC_ACQUIRE, __HIP_MEMORY_SCOPE_AGENT) < t + 1) {
        __builtin_amdgcn_s_sleep(1);
      }
    }
    __syncthreads();   // all threads held until peer's gates are visible
    if (tid < HH) {
      float own_a  = gown[tid];
      float own_b  = gown[HH + tid];
      float peer_a = peer_in[(t & 1) * 512 + tid];
      float peer_b = peer_in[(t & 1) * 512 + HH + tid];
      // half0: own=(i,f) peer=(g,o); half1: own=(g,o) peer=(i,f)
      float ig = half ? peer_a : own_a;
      float fg = half ? peer_b : own_b;
      float gg = half ? own_a  : peer_a;
      float og = half ? own_b  : peer_b;
      c_reg = c_reg * fast_sig(fg) + fast_sig(ig) * fast_tanh(gg);
      float hv = fast_sig(og) * fast_tanh(c_reg);
      ((__half*)h4)[tid] = __float2half(hv);
      if (half == 0) hbuf[t & 15][tid] = hv;
    }
    __syncthreads();   // h ready for next step; hbuf complete
    if (half == 0 && (t & 15) == 15) {
      int t0v = t - 15;
#pragma unroll
      for (int q = 0; q < 2; ++q) {
        int idx = tid + q * 512;        // 0..1023
        int jj  = idx >> 2;
        int s0  = (idx & 3) << 2;
        float4 v;
        v.x = hbuf[s0 + 0][jj];
        v.y = hbuf[s0 + 1][jj];
        v.z = hbuf[s0 + 2][jj];
        v.w = hbuf[s0 + 3][jj];
        *(float4*)(outb + (size_t)jj * TT + t0v + s0) = v;   // full-line stores
      }
    }
  }
  if (half == 0 && tid < HH) out[(size_t)BB * HH * TT + b * HH + tid] = c_reg;
}

// ---------------------------------------------------------------------------
extern "C" void kernel_launch(void* const* d_in, const int* in_sizes, int n_in,
                              void* d_out, int out_size, void* d_ws, size_t ws_size,
                              hipStream_t stream) {
  const float* x    = (const float*)d_in[0];
  const float* h0   = (const float*)d_in[1];
  const float* c0   = (const float*)d_in[2];
  const float* W_ih = (const float*)d_in[3];
  const float* W_hh = (const float*)d_in[4];
  const float* b_h  = (const float*)d_in[5];
  float* out = (float*)d_out;

  // Workspace layout:
  //   [0,   32 MB)   Wc   : f16 W_hh transposed, (B,4H,H)
  //   [32,  96 MB)   WXh  : f16 precomputed wx+bias, (B,T,4H)
  //   [96 MB, +512K) xch  : gate exchange, (B, 2 halves, 2 parity, 512) f32
  //   then           flags: (B, 2) int
  char* ws = (char*)d_ws;
  __half* Wc   = (__half*)ws;
  __half* WXh  = (__half*)(ws + (size_t)32 * 1024 * 1024);
  float*  xch  = (float*)(ws + (size_t)96 * 1024 * 1024);
  int*    flags = (int*)(ws + (size_t)96 * 1024 * 1024 + 512 * 1024);

  hipMemsetAsync(flags, 0, BB * 2 * sizeof(int), stream);
  transpose_whh<<<dim3(G4 / 32, HH / 32, BB), dim3(32, 8), 0, stream>>>(W_hh, Wc);
  gemm_wx<<<dim3(G4 / 64, TT / 64, BB), dim3(256), 0, stream>>>(x, W_ih, b_h, WXh);
  lstm_rec2<<<dim3(128), dim3(512), 0, stream>>>(Wc, WXh, h0, c0, out, xch, flags);
}

// Round 4
// 2431.080 us; speedup vs baseline: 1.0097x; 1.0097x over previous
//
#include <hip/hip_runtime.h>
#include <hip/hip_fp16.h>

// Problem constants
#define BB  64
#define CIN 256
#define HH  256
#define TT  512
#define G4  1024   // 4*H

typedef _Float16 half2_t __attribute__((ext_vector_type(2)));

__device__ __forceinline__ float dot2f(float wa, float hb, float acc) {
  half2_t a = __builtin_bit_cast(half2_t, wa);
  half2_t b = __builtin_bit_cast(half2_t, hb);
#if __has_builtin(__builtin_amdgcn_fdot2)
  return __builtin_amdgcn_fdot2(a, b, acc, false);
#else
  return acc + (float)a.x * (float)b.x + (float)a.y * (float)b.y;
#endif
}

__device__ __forceinline__ float fast_rcp(float x) { return __builtin_amdgcn_rcpf(x); }
__device__ __forceinline__ float fast_sig(float x) {
  return fast_rcp(1.0f + exp2f(-1.4426950408889634f * x));
}
__device__ __forceinline__ float fast_tanh(float x) {
  return 1.0f - 2.0f * fast_rcp(1.0f + exp2f(2.8853900817779268f * x));
}

// ---------------------------------------------------------------------------
// Kernel 0: W_hh (B,H,4H) fp32 -> Wc (B,4H,H) f16  (per-gate-col contiguous)
// ---------------------------------------------------------------------------
__global__ __launch_bounds__(256) void transpose_whh(const float* __restrict__ W,
                                                     __half* __restrict__ Wc) {
  __shared__ __half tile[32][33];
  int b  = blockIdx.z;
  int j0 = blockIdx.x * 32;
  int k0 = blockIdx.y * 32;
  int tx = threadIdx.x;
  int ty = threadIdx.y;
  const float* Wb = W + (size_t)b * HH * G4;
#pragma unroll
  for (int r = 0; r < 32; r += 8)
    tile[ty + r][tx] = __float2half(Wb[(size_t)(k0 + ty + r) * G4 + j0 + tx]);
  __syncthreads();
  __half* out = Wc + (size_t)b * G4 * HH;
#pragma unroll
  for (int r = 0; r < 32; r += 8)
    out[(size_t)(j0 + ty + r) * HH + k0 + tx] = tile[tx][ty + r];
}

// ---------------------------------------------------------------------------
// Kernel 1: WXT[b][j][t] = sum_i x[b][i][t] * W_ih[b][i][j] + b_h[b][j], f16.
// fp32 LDS GEMM (64t x 64j tile) + LDS transpose epilogue so the output is
// (B, 4H, T) with t contiguous — the recurrence reads 8 steps per float4.
// ---------------------------------------------------------------------------
__global__ __launch_bounds__(256) void gemm_wx(const float* __restrict__ X,
                                               const float* __restrict__ Wih,
                                               const float* __restrict__ bh,
                                               __half* __restrict__ WXT) {
  __shared__ float As[16][64];        // As[k][t]
  __shared__ float Bs[16][64];        // Bs[k][j]
  __shared__ __half tile[64][72];     // [j][t], pitch 144 B (16B-aligned)
  int b  = blockIdx.z;
  int t0 = blockIdx.y * 64;
  int j0 = blockIdx.x * 64;
  int tid = threadIdx.x;
  int tx = tid & 15;   // j group
  int ty = tid >> 4;   // t group
  const float* Xb = X   + (size_t)b * CIN * TT;
  const float* Wb = Wih + (size_t)b * CIN * G4;
  float acc[4][4] = {};
  for (int i0 = 0; i0 < CIN; i0 += 16) {
#pragma unroll
    for (int q = 0; q < 4; ++q) {
      int lin = tid + q * 256;
      int k  = lin >> 6;
      int tt = lin & 63;
      As[k][tt] = Xb[(size_t)(i0 + k) * TT + t0 + tt];
      Bs[k][tt] = Wb[(size_t)(i0 + k) * G4 + j0 + tt];
    }
    __syncthreads();
#pragma unroll
    for (int k = 0; k < 16; ++k) {
      float4 av = *(const float4*)&As[k][ty * 4];
      float4 bv = *(const float4*)&Bs[k][tx * 4];
      float a[4] = {av.x, av.y, av.z, av.w};
      float c[4] = {bv.x, bv.y, bv.z, bv.w};
#pragma unroll
      for (int r = 0; r < 4; ++r)
#pragma unroll
        for (int cc = 0; cc < 4; ++cc)
          acc[r][cc] = fmaf(a[r], c[cc], acc[r][cc]);
    }
    __syncthreads();
  }
  // epilogue: bias + f16, staged through LDS as [j][t]
  const float* bias = bh + (size_t)b * G4;
#pragma unroll
  for (int cc = 0; cc < 4; ++cc) {
    float bv = bias[j0 + tx * 4 + cc];
    __half2 p0 = __floats2half2_rn(acc[0][cc] + bv, acc[1][cc] + bv);
    __half2 p1 = __floats2half2_rn(acc[2][cc] + bv, acc[3][cc] + bv);
    float2 st;
    st.x = __builtin_bit_cast(float, p0);
    st.y = __builtin_bit_cast(float, p1);
    *(float2*)&tile[tx * 4 + cc][ty * 4] = st;   // t = ty*4 + 0..3
  }
  __syncthreads();
  int jj = tid >> 2;            // 0..63
  int tg = (tid & 3) * 16;      // 0,16,32,48
  __half* dst = WXT + ((size_t)b * G4 + j0 + jj) * TT + t0 + tg;
  *(float4*)dst       = *(const float4*)&tile[jj][tg];
  *(float4*)(dst + 8) = *(const float4*)&tile[jj][tg + 8];
}

// ---------------------------------------------------------------------------
// Kernel 2: recurrence, W_hh VGPR-resident (pinned with empty inline asm so
// the compiler cannot rematerialize/sink the loads — R2's VGPR_Count=84
// proved it did exactly that). 128 WGs x 512 threads, 2 WGs per batch,
// cross-WG gate exchange via agent-scope release/acquire (measured ~0.1us).
// wx prefetched 8 steps at a time (float4 from the (B,4H,T) layout),
// double-buffered across 8-step groups.
// ---------------------------------------------------------------------------
__global__ __launch_bounds__(512, 2) void lstm_rec3(const __half* __restrict__ Wc,
                                                    const __half* __restrict__ WXT,
                                                    const float* __restrict__ h0,
                                                    const float* __restrict__ c0,
                                                    float* __restrict__ out,
                                                    float* __restrict__ xch,
                                                    int* __restrict__ flags) {
  __shared__ float4 h4[32];        // h as 256 f16
  __shared__ float  gown[512];     // own-half gates
  __shared__ float  hbuf[16][256]; // 16-step h staging (half 0 flushes)
  int g    = blockIdx.x;
  int b    = g & 63;
  int half = g >> 6;
  int tid  = threadIdx.x;
  int j    = half * 512 + tid;

  // W column -> 128 pinned VGPRs
  const float4* wp = (const float4*)(Wc + ((size_t)b * G4 + j) * HH);
  float wr[128];
#pragma unroll
  for (int m = 0; m < 32; ++m) {
    float4 v = wp[m];
    wr[4 * m + 0] = v.x;
    wr[4 * m + 1] = v.y;
    wr[4 * m + 2] = v.z;
    wr[4 * m + 3] = v.w;
  }
#pragma unroll
  for (int q = 0; q < 128; ++q) asm volatile("" : "+v"(wr[q]));

  float c_reg = 0.0f;
  if (tid < HH) {
    c_reg = c0[b * HH + tid];
    ((__half*)h4)[tid] = __float2half(h0[b * HH + tid]);
  }
  __syncthreads();

  float*       my_out  = xch + ((size_t)(b * 2 + half) * 2) * 512;
  const float* peer_in = xch + ((size_t)(b * 2 + (half ^ 1)) * 2) * 512;
  int* my_flag   = flags + (b * 2 + half);
  int* peer_flag = flags + (b * 2 + (half ^ 1));
  const __half* wxTb = WXT + ((size_t)b * G4 + j) * TT;
  float* outb = out + (size_t)b * HH * TT;

  float4 wxcur = *(const float4*)(wxTb);   // steps 0..7
  for (int t8 = 0; t8 < 64; ++t8) {
    // prefetch next 8-step group (wraps harmlessly at the end)
    float4 wxnext = *(const float4*)(wxTb + ((size_t)((t8 + 1) & 63) * 8));
#pragma unroll
    for (int u = 0; u < 8; ++u) {
      int t = t8 * 8 + u;
      float fw = (u < 2) ? wxcur.x : (u < 4) ? wxcur.y : (u < 6) ? wxcur.z : wxcur.w;
      half2_t hp = __builtin_bit_cast(half2_t, fw);
      float wx = (float)((u & 1) ? hp.y : hp.x);

      float a0 = 0.f, a1 = 0.f, a2 = 0.f, a3 = 0.f;
#pragma unroll
      for (int m = 0; m < 32; m += 4) {
        float4 x0 = h4[m + 0], x1 = h4[m + 1], x2 = h4[m + 2], x3 = h4[m + 3];
        a0 = dot2f(wr[4 * m + 0], x0.x, a0);
        a0 = dot2f(wr[4 * m + 1], x0.y, a0);
        a0 = dot2f(wr[4 * m + 2], x0.z, a0);
        a0 = dot2f(wr[4 * m + 3], x0.w, a0);
        a1 = dot2f(wr[4 * m + 4], x1.x, a1);
        a1 = dot2f(wr[4 * m + 5], x1.y, a1);
        a1 = dot2f(wr[4 * m + 6], x1.z, a1);
        a1 = dot2f(wr[4 * m + 7], x1.w, a1);
        a2 = dot2f(wr[4 * m + 8], x2.x, a2);
        a2 = dot2f(wr[4 * m + 9], x2.y, a2);
        a2 = dot2f(wr[4 * m + 10], x2.z, a2);
        a2 = dot2f(wr[4 * m + 11], x2.w, a2);
        a3 = dot2f(wr[4 * m + 12], x3.x, a3);
        a3 = dot2f(wr[4 * m + 13], x3.y, a3);
        a3 = dot2f(wr[4 * m + 14], x3.z, a3);
        a3 = dot2f(wr[4 * m + 15], x3.w, a3);
      }
      float gate = fast_tanh((a0 + a1) + (a2 + a3) + wx);
      gown[tid] = gate;
      my_out[(t & 1) * 512 + tid] = gate;
      __syncthreads();   // LDS visible + drains the gate stores
      if (tid == 0) {
        __hip_atomic_store(my_flag, t + 1, __ATOMIC_RELEASE, __HIP_MEMORY_SCOPE_AGENT);
        while (__hip_atomic_load(peer_flag, __ATOMIC_ACQUIRE, __HIP_MEMORY_SCOPE_AGENT) < t + 1) {
          __builtin_amdgcn_s_sleep(1);
        }
      }
      __syncthreads();   // all threads held until peer's gates visible
      if (tid < HH) {
        float own_a  = gown[tid];
        float own_b  = gown[HH + tid];
        float peer_a = peer_in[(t & 1) * 512 + tid];
        float peer_b = peer_in[(t & 1) * 512 + HH + tid];
        float ig = half ? peer_a : own_a;
        float fg = half ? peer_b : own_b;
        float gg = half ? own_a  : peer_a;
        float og = half ? own_b  : peer_b;
        c_reg = c_reg * fast_sig(fg) + fast_sig(ig) * fast_tanh(gg);
        float hv = fast_sig(og) * fast_tanh(c_reg);
        ((__half*)h4)[tid] = __float2half(hv);
        if (half == 0) hbuf[t & 15][tid] = hv;
      }
      __syncthreads();   // h ready for next step; hbuf complete
      if (half == 0 && (t & 15) == 15) {
        int t0v = t - 15;
#pragma unroll
        for (int q = 0; q < 2; ++q) {
          int idx = tid + q * 512;
          int jj  = idx >> 2;
          int s0  = (idx & 3) << 2;
          float4 v;
          v.x = hbuf[s0 + 0][jj];
          v.y = hbuf[s0 + 1][jj];
          v.z = hbuf[s0 + 2][jj];
          v.w = hbuf[s0 + 3][jj];
          *(float4*)(outb + (size_t)jj * TT + t0v + s0) = v;
        }
      }
    }
    wxcur = wxnext;
  }
  if (half == 0 && tid < HH) out[(size_t)BB * HH * TT + b * HH + tid] = c_reg;
}

// ---------------------------------------------------------------------------
extern "C" void kernel_launch(void* const* d_in, const int* in_sizes, int n_in,
                              void* d_out, int out_size, void* d_ws, size_t ws_size,
                              hipStream_t stream) {
  const float* x    = (const float*)d_in[0];
  const float* h0   = (const float*)d_in[1];
  const float* c0   = (const float*)d_in[2];
  const float* W_ih = (const float*)d_in[3];
  const float* W_hh = (const float*)d_in[4];
  const float* b_h  = (const float*)d_in[5];
  float* out = (float*)d_out;

  // Workspace layout:
  //   [0,   32 MB)   Wc   : f16 W_hh transposed, (B,4H,H)
  //   [32,  96 MB)   WXT  : f16 wx+bias, (B,4H,T)  -- t contiguous
  //   [96 MB, +512K) xch  : gate exchange
  //   then           flags: (B,2) int
  char* ws = (char*)d_ws;
  __half* Wc    = (__half*)ws;
  __half* WXT   = (__half*)(ws + (size_t)32 * 1024 * 1024);
  float*  xch   = (float*)(ws + (size_t)96 * 1024 * 1024);
  int*    flags = (int*)(ws + (size_t)96 * 1024 * 1024 + 512 * 1024);

  hipMemsetAsync(flags, 0, BB * 2 * sizeof(int), stream);
  transpose_whh<<<dim3(G4 / 32, HH / 32, BB), dim3(32, 8), 0, stream>>>(W_hh, Wc);
  gemm_wx<<<dim3(G4 / 64, TT / 64, BB), dim3(256), 0, stream>>>(x, W_ih, b_h, WXT);
  lstm_rec3<<<dim3(128), dim3(512), 0, stream>>>(Wc, WXT, h0, c0, out, xch, flags);
}

// Round 5
// 2420.445 us; speedup vs baseline: 1.0142x; 1.0044x over previous
//
#include <hip/hip_runtime.h>
#include <hip/hip_fp16.h>

// Problem constants
#define BB  64
#define CIN 256
#define HH  256
#define TT  512
#define G4  1024   // 4*H

typedef _Float16 half2_t __attribute__((ext_vector_type(2)));

__device__ __forceinline__ float dot2f(float wa, float hb, float acc) {
  half2_t a = __builtin_bit_cast(half2_t, wa);
  half2_t b = __builtin_bit_cast(half2_t, hb);
#if __has_builtin(__builtin_amdgcn_fdot2)
  return __builtin_amdgcn_fdot2(a, b, acc, false);
#else
  return acc + (float)a.x * (float)b.x + (float)a.y * (float)b.y;
#endif
}

__device__ __forceinline__ float fast_rcp(float x) { return __builtin_amdgcn_rcpf(x); }
__device__ __forceinline__ float fast_sig(float x) {
  return fast_rcp(1.0f + exp2f(-1.4426950408889634f * x));
}
__device__ __forceinline__ float fast_tanh(float x) {
  return 1.0f - 2.0f * fast_rcp(1.0f + exp2f(2.8853900817779268f * x));
}

// ---------------------------------------------------------------------------
// Kernel 0: W_hh (B,H,4H) fp32 -> Wc (B,4H,H) f16  (per-gate-col contiguous)
// ---------------------------------------------------------------------------
__global__ __launch_bounds__(256) void transpose_whh(const float* __restrict__ W,
                                                     __half* __restrict__ Wc) {
  __shared__ __half tile[32][33];
  int b  = blockIdx.z;
  int j0 = blockIdx.x * 32;
  int k0 = blockIdx.y * 32;
  int tx = threadIdx.x;
  int ty = threadIdx.y;
  const float* Wb = W + (size_t)b * HH * G4;
#pragma unroll
  for (int r = 0; r < 32; r += 8)
    tile[ty + r][tx] = __float2half(Wb[(size_t)(k0 + ty + r) * G4 + j0 + tx]);
  __syncthreads();
  __half* out = Wc + (size_t)b * G4 * HH;
#pragma unroll
  for (int r = 0; r < 32; r += 8)
    out[(size_t)(j0 + ty + r) * HH + k0 + tx] = tile[tx][ty + r];
}

// ---------------------------------------------------------------------------
// Kernel 1: WXT[b][j][t] = sum_i x[b][i][t] * W_ih[b][i][j] + b_h[b][j], f16.
// fp32 LDS GEMM (64t x 64j tile) + LDS transpose epilogue -> (B,4H,T) layout.
// ---------------------------------------------------------------------------
__global__ __launch_bounds__(256) void gemm_wx(const float* __restrict__ X,
                                               const float* __restrict__ Wih,
                                               const float* __restrict__ bh,
                                               __half* __restrict__ WXT) {
  __shared__ float As[16][64];
  __shared__ float Bs[16][64];
  __shared__ __half tile[64][72];
  int b  = blockIdx.z;
  int t0 = blockIdx.y * 64;
  int j0 = blockIdx.x * 64;
  int tid = threadIdx.x;
  int tx = tid & 15;
  int ty = tid >> 4;
  const float* Xb = X   + (size_t)b * CIN * TT;
  const float* Wb = Wih + (size_t)b * CIN * G4;
  float acc[4][4] = {};
  for (int i0 = 0; i0 < CIN; i0 += 16) {
#pragma unroll
    for (int q = 0; q < 4; ++q) {
      int lin = tid + q * 256;
      int k  = lin >> 6;
      int tt = lin & 63;
      As[k][tt] = Xb[(size_t)(i0 + k) * TT + t0 + tt];
      Bs[k][tt] = Wb[(size_t)(i0 + k) * G4 + j0 + tt];
    }
    __syncthreads();
#pragma unroll
    for (int k = 0; k < 16; ++k) {
      float4 av = *(const float4*)&As[k][ty * 4];
      float4 bv = *(const float4*)&Bs[k][tx * 4];
      float a[4] = {av.x, av.y, av.z, av.w};
      float c[4] = {bv.x, bv.y, bv.z, bv.w};
#pragma unroll
      for (int r = 0; r < 4; ++r)
#pragma unroll
        for (int cc = 0; cc < 4; ++cc)
          acc[r][cc] = fmaf(a[r], c[cc], acc[r][cc]);
    }
    __syncthreads();
  }
  const float* bias = bh + (size_t)b * G4;
#pragma unroll
  for (int cc = 0; cc < 4; ++cc) {
    float bv = bias[j0 + tx * 4 + cc];
    __half2 p0 = __floats2half2_rn(acc[0][cc] + bv, acc[1][cc] + bv);
    __half2 p1 = __floats2half2_rn(acc[2][cc] + bv, acc[3][cc] + bv);
    float2 st;
    st.x = __builtin_bit_cast(float, p0);
    st.y = __builtin_bit_cast(float, p1);
    *(float2*)&tile[tx * 4 + cc][ty * 4] = st;
  }
  __syncthreads();
  int jj = tid >> 2;
  int tg = (tid & 3) * 16;
  __half* dst = WXT + ((size_t)b * G4 + j0 + jj) * TT + t0 + tg;
  *(float4*)dst       = *(const float4*)&tile[jj][tg];
  *(float4*)(dst + 8) = *(const float4*)&tile[jj][tg + 8];
}

// ---------------------------------------------------------------------------
// Kernel 2: recurrence. W_hh held in 32 NAMED float4 SSA values (no array ->
// no alloca -> cannot silently live in scratch; R2/R3 proved both plain loads
// and asm-pinned ARRAYS end up re-streamed from memory every step: VGPR=84/92,
// 4 us/step unchanged). Each component pinned once with empty inline asm so
// the loads cannot be rematerialized into the t-loop.
// ---------------------------------------------------------------------------
#define LOADW(m)                                                            \
  float4 w##m = wp[m];                                                      \
  asm volatile("" : "+v"(w##m.x), "+v"(w##m.y), "+v"(w##m.z), "+v"(w##m.w));

#define DOT4(m)                                                             \
  {                                                                         \
    float4 xh = h4[m];                                                      \
    a0 = dot2f(w##m.x, xh.x, a0);                                           \
    a1 = dot2f(w##m.y, xh.y, a1);                                           \
    a2 = dot2f(w##m.z, xh.z, a2);                                           \
    a3 = dot2f(w##m.w, xh.w, a3);                                           \
  }

__global__ __launch_bounds__(512, 2) void lstm_rec4(const __half* __restrict__ Wc,
                                                    const __half* __restrict__ WXT,
                                                    const float* __restrict__ h0,
                                                    const float* __restrict__ c0,
                                                    float* __restrict__ out,
                                                    float* __restrict__ xch,
                                                    int* __restrict__ flags) {
  __shared__ float4 h4[32];        // h as 256 f16
  __shared__ float  gown[512];     // own-half gates
  __shared__ float  hbuf[16][256]; // 16-step h staging (half 0 flushes)
  int g    = blockIdx.x;
  int b    = g & 63;
  int half = g >> 6;
  int tid  = threadIdx.x;
  int j    = half * 512 + tid;

  const float4* wp = (const float4*)(Wc + ((size_t)b * G4 + j) * HH);
  LOADW(0)  LOADW(1)  LOADW(2)  LOADW(3)  LOADW(4)  LOADW(5)  LOADW(6)  LOADW(7)
  LOADW(8)  LOADW(9)  LOADW(10) LOADW(11) LOADW(12) LOADW(13) LOADW(14) LOADW(15)
  LOADW(16) LOADW(17) LOADW(18) LOADW(19) LOADW(20) LOADW(21) LOADW(22) LOADW(23)
  LOADW(24) LOADW(25) LOADW(26) LOADW(27) LOADW(28) LOADW(29) LOADW(30) LOADW(31)

  float c_reg = 0.0f;
  if (tid < HH) {
    c_reg = c0[b * HH + tid];
    ((__half*)h4)[tid] = __float2half(h0[b * HH + tid]);
  }
  __syncthreads();

  float*       my_out  = xch + ((size_t)(b * 2 + half) * 2) * 512;
  const float* peer_in = xch + ((size_t)(b * 2 + (half ^ 1)) * 2) * 512;
  int* my_flag   = flags + (b * 2 + half);
  int* peer_flag = flags + (b * 2 + (half ^ 1));
  const __half* wxTb = WXT + ((size_t)b * G4 + j) * TT;
  float* outb = out + (size_t)b * HH * TT;

  float4 wxcur = *(const float4*)(wxTb);   // steps 0..7
  for (int t8 = 0; t8 < 64; ++t8) {
    float4 wxnext = *(const float4*)(wxTb + ((size_t)((t8 + 1) & 63) * 8));
#pragma unroll
    for (int u = 0; u < 8; ++u) {
      int t = t8 * 8 + u;
      float fw = (u < 2) ? wxcur.x : (u < 4) ? wxcur.y : (u < 6) ? wxcur.z : wxcur.w;
      half2_t hp = __builtin_bit_cast(half2_t, fw);
      float wx = (float)((u & 1) ? hp.y : hp.x);

      float a0 = 0.f, a1 = 0.f, a2 = 0.f, a3 = 0.f;
      DOT4(0)  DOT4(1)  DOT4(2)  DOT4(3)  DOT4(4)  DOT4(5)  DOT4(6)  DOT4(7)
      DOT4(8)  DOT4(9)  DOT4(10) DOT4(11) DOT4(12) DOT4(13) DOT4(14) DOT4(15)
      DOT4(16) DOT4(17) DOT4(18) DOT4(19) DOT4(20) DOT4(21) DOT4(22) DOT4(23)
      DOT4(24) DOT4(25) DOT4(26) DOT4(27) DOT4(28) DOT4(29) DOT4(30) DOT4(31)

      float gate = fast_tanh((a0 + a1) + (a2 + a3) + wx);
      gown[tid] = gate;
      my_out[(t & 1) * 512 + tid] = gate;
      __syncthreads();   // LDS visible + drains the gate stores
      if (tid == 0) {
        __hip_atomic_store(my_flag, t + 1, __ATOMIC_RELEASE, __HIP_MEMORY_SCOPE_AGENT);
        while (__hip_atomic_load(peer_flag, __ATOMIC_ACQUIRE, __HIP_MEMORY_SCOPE_AGENT) < t + 1) {
          __builtin_amdgcn_s_sleep(1);
        }
      }
      __syncthreads();   // all threads held until peer's gates visible
      if (tid < HH) {
        float own_a  = gown[tid];
        float own_b  = gown[HH + tid];
        float peer_a = peer_in[(t & 1) * 512 + tid];
        float peer_b = peer_in[(t & 1) * 512 + HH + tid];
        float ig = half ? peer_a : own_a;
        float fg = half ? peer_b : own_b;
        float gg = half ? own_a  : peer_a;
        float og = half ? own_b  : peer_b;
        c_reg = c_reg * fast_sig(fg) + fast_sig(ig) * fast_tanh(gg);
        float hv = fast_sig(og) * fast_tanh(c_reg);
        ((__half*)h4)[tid] = __float2half(hv);
        if (half == 0) hbuf[t & 15][tid] = hv;
      }
      __syncthreads();   // h ready for next step; hbuf complete
      if (half == 0 && (t & 15) == 15) {
        int t0v = t - 15;
#pragma unroll
        for (int q = 0; q < 2; ++q) {
          int idx = tid + q * 512;
          int jj  = idx >> 2;
          int s0  = (idx & 3) << 2;
          float4 v;
          v.x = hbuf[s0 + 0][jj];
          v.y = hbuf[s0 + 1][jj];
          v.z = hbuf[s0 + 2][jj];
          v.w = hbuf[s0 + 3][jj];
          *(float4*)(outb + (size_t)jj * TT + t0v + s0) = v;
        }
      }
    }
    wxcur = wxnext;
  }
  if (half == 0 && tid < HH) out[(size_t)BB * HH * TT + b * HH + tid] = c_reg;
}

// ---------------------------------------------------------------------------
extern "C" void kernel_launch(void* const* d_in, const int* in_sizes, int n_in,
                              void* d_out, int out_size, void* d_ws, size_t ws_size,
                              hipStream_t stream) {
  const float* x    = (const float*)d_in[0];
  const float* h0   = (const float*)d_in[1];
  const float* c0   = (const float*)d_in[2];
  const float* W_ih = (const float*)d_in[3];
  const float* W_hh = (const float*)d_in[4];
  const float* b_h  = (const float*)d_in[5];
  float* out = (float*)d_out;

  // Workspace layout:
  //   [0,   32 MB)   Wc   : f16 W_hh transposed, (B,4H,H)
  //   [32,  96 MB)   WXT  : f16 wx+bias, (B,4H,T)  -- t contiguous
  //   [96 MB, +512K) xch  : gate exchange
  //   then           flags: (B,2) int
  char* ws = (char*)d_ws;
  __half* Wc    = (__half*)ws;
  __half* WXT   = (__half*)(ws + (size_t)32 * 1024 * 1024);
  float*  xch   = (float*)(ws + (size_t)96 * 1024 * 1024);
  int*    flags = (int*)(ws + (size_t)96 * 1024 * 1024 + 512 * 1024);

  hipMemsetAsync(flags, 0, BB * 2 * sizeof(int), stream);
  transpose_whh<<<dim3(G4 / 32, HH / 32, BB), dim3(32, 8), 0, stream>>>(W_hh, Wc);
  gemm_wx<<<dim3(G4 / 64, TT / 64, BB), dim3(256), 0, stream>>>(x, W_ih, b_h, WXT);
  lstm_rec4<<<dim3(128), dim3(512), 0, stream>>>(Wc, WXT, h0, c0, out, xch, flags);
}

// Round 6
// 2383.691 us; speedup vs baseline: 1.0298x; 1.0154x over previous
//
#include <hip/hip_runtime.h>
#include <hip/hip_fp16.h>

// Problem constants
#define BB  64
#define CIN 256
#define HH  256
#define TT  512
#define G4  1024   // 4*H

typedef _Float16 half2_t __attribute__((ext_vector_type(2)));

__device__ __forceinline__ float fdot2i(int wi, int hi, float acc) {
  half2_t a = __builtin_bit_cast(half2_t, wi);
  half2_t b = __builtin_bit_cast(half2_t, hi);
  return __builtin_amdgcn_fdot2(a, b, acc, false);
}

__device__ __forceinline__ float fast_rcp(float x) { return __builtin_amdgcn_rcpf(x); }
__device__ __forceinline__ float fast_sig(float x) {
  return fast_rcp(1.0f + exp2f(-1.4426950408889634f * x));
}
__device__ __forceinline__ float fast_tanh(float x) {
  return 1.0f - 2.0f * fast_rcp(1.0f + exp2f(2.8853900817779268f * x));
}

// ---------------------------------------------------------------------------
// Kernel 0: W_hh (B,H,4H) fp32 -> Wc (B,4H,H) f16  (per-gate-col contiguous)
// ---------------------------------------------------------------------------
__global__ __launch_bounds__(256) void transpose_whh(const float* __restrict__ W,
                                                     __half* __restrict__ Wc) {
  __shared__ __half tile[32][33];
  int b  = blockIdx.z;
  int j0 = blockIdx.x * 32;
  int k0 = blockIdx.y * 32;
  int tx = threadIdx.x;
  int ty = threadIdx.y;
  const float* Wb = W + (size_t)b * HH * G4;
#pragma unroll
  for (int r = 0; r < 32; r += 8)
    tile[ty + r][tx] = __float2half(Wb[(size_t)(k0 + ty + r) * G4 + j0 + tx]);
  __syncthreads();
  __half* out = Wc + (size_t)b * G4 * HH;
#pragma unroll
  for (int r = 0; r < 32; r += 8)
    out[(size_t)(j0 + ty + r) * HH + k0 + tx] = tile[tx][ty + r];
}

// ---------------------------------------------------------------------------
// Kernel 1: WXT[b][j][t] = sum_i x[b][i][t] * W_ih[b][i][j] + b_h[b][j], f16.
// fp32 LDS GEMM (64t x 64j tile) + LDS transpose epilogue -> (B,4H,T) layout.
// ---------------------------------------------------------------------------
__global__ __launch_bounds__(256) void gemm_wx(const float* __restrict__ X,
                                               const float* __restrict__ Wih,
                                               const float* __restrict__ bh,
                                               __half* __restrict__ WXT) {
  __shared__ float As[16][64];
  __shared__ float Bs[16][64];
  __shared__ __half tile[64][72];
  int b  = blockIdx.z;
  int t0 = blockIdx.y * 64;
  int j0 = blockIdx.x * 64;
  int tid = threadIdx.x;
  int tx = tid & 15;
  int ty = tid >> 4;
  const float* Xb = X   + (size_t)b * CIN * TT;
  const float* Wb = Wih + (size_t)b * CIN * G4;
  float acc[4][4] = {};
  for (int i0 = 0; i0 < CIN; i0 += 16) {
#pragma unroll
    for (int q = 0; q < 4; ++q) {
      int lin = tid + q * 256;
      int k  = lin >> 6;
      int tt = lin & 63;
      As[k][tt] = Xb[(size_t)(i0 + k) * TT + t0 + tt];
      Bs[k][tt] = Wb[(size_t)(i0 + k) * G4 + j0 + tt];
    }
    __syncthreads();
#pragma unroll
    for (int k = 0; k < 16; ++k) {
      float4 av = *(const float4*)&As[k][ty * 4];
      float4 bv = *(const float4*)&Bs[k][tx * 4];
      float a[4] = {av.x, av.y, av.z, av.w};
      float c[4] = {bv.x, bv.y, bv.z, bv.w};
#pragma unroll
      for (int r = 0; r < 4; ++r)
#pragma unroll
        for (int cc = 0; cc < 4; ++cc)
          acc[r][cc] = fmaf(a[r], c[cc], acc[r][cc]);
    }
    __syncthreads();
  }
  const float* bias = bh + (size_t)b * G4;
#pragma unroll
  for (int cc = 0; cc < 4; ++cc) {
    float bv = bias[j0 + tx * 4 + cc];
    __half2 p0 = __floats2half2_rn(acc[0][cc] + bv, acc[1][cc] + bv);
    __half2 p1 = __floats2half2_rn(acc[2][cc] + bv, acc[3][cc] + bv);
    float2 st;
    st.x = __builtin_bit_cast(float, p0);
    st.y = __builtin_bit_cast(float, p1);
    *(float2*)&tile[tx * 4 + cc][ty * 4] = st;
  }
  __syncthreads();
  int jj = tid >> 2;
  int tg = (tid & 3) * 16;
  __half* dst = WXT + ((size_t)b * G4 + j0 + jj) * TT + t0 + tg;
  *(float4*)dst       = *(const float4*)&tile[jj][tg];
  *(float4*)(dst + 8) = *(const float4*)&tile[jj][tg + 8];
}

// ---------------------------------------------------------------------------
// Kernel 2: recurrence.
//  - W in 32 named int4 (128 VGPRs). amdgpu_waves_per_eu(2,2) clamps the
//    backend's occupancy target to 2 waves/EU (VGPR budget 256): R2-R5 proved
//    launch_bounds' min-waves alone lets the allocator spill W to scratch to
//    chase 6 waves/EU (VGPR_Count=84≈512/6, 4us/step from scratch reload).
//  - h broadcast WITHOUT the LDS pipe: one ds_read_b64 per wave (lane l holds
//    h[4l..4l+3]), then readlane -> wave-uniform operand of v_dot2_f32_f16.
//    (R5's per-thread LDS h-reads were 256 KB/step/CU through one LDS pipe.)
//  - 2 WGs/batch, proven-cheap agent-scope flag exchange, hbuf line flush.
// ---------------------------------------------------------------------------
#define LOADW(m)                                                             \
  int4 w##m = wp[m];                                                         \
  asm volatile("" : "+v"(w##m.x), "+v"(w##m.y), "+v"(w##m.z), "+v"(w##m.w));

#define DOTBLK(m)                                                            \
  {                                                                          \
    int s0 = __builtin_amdgcn_readlane(hA, 2 * m);                           \
    int s1 = __builtin_amdgcn_readlane(hB, 2 * m);                           \
    int s2 = __builtin_amdgcn_readlane(hA, 2 * m + 1);                       \
    int s3 = __builtin_amdgcn_readlane(hB, 2 * m + 1);                       \
    a0 = fdot2i(w##m.x, s0, a0);                                             \
    a1 = fdot2i(w##m.y, s1, a1);                                             \
    a2 = fdot2i(w##m.z, s2, a2);                                             \
    a3 = fdot2i(w##m.w, s3, a3);                                             \
  }

__global__ __attribute__((amdgpu_waves_per_eu(2, 2)))
__launch_bounds__(512) void lstm_rec5(const __half* __restrict__ Wc,
                                      const __half* __restrict__ WXT,
                                      const float* __restrict__ h0,
                                      const float* __restrict__ c0,
                                      float* __restrict__ out,
                                      float* __restrict__ xch,
                                      int* __restrict__ flags) {
  __shared__ __half hsh[256];      // h, f16
  __shared__ float  gown[512];     // own-half gates
  __shared__ float  hbuf[16][256]; // 16-step h staging (half 0 flushes)
  int g    = blockIdx.x;
  int b    = g & 63;
  int half = g >> 6;
  int tid  = threadIdx.x;
  int lane = tid & 63;
  int j    = half * 512 + tid;

  // W column -> 32 named int4 = 128 VGPRs
  const int4* wp = (const int4*)(Wc + ((size_t)b * G4 + j) * HH);
  LOADW(0)  LOADW(1)  LOADW(2)  LOADW(3)  LOADW(4)  LOADW(5)  LOADW(6)  LOADW(7)
  LOADW(8)  LOADW(9)  LOADW(10) LOADW(11) LOADW(12) LOADW(13) LOADW(14) LOADW(15)
  LOADW(16) LOADW(17) LOADW(18) LOADW(19) LOADW(20) LOADW(21) LOADW(22) LOADW(23)
  LOADW(24) LOADW(25) LOADW(26) LOADW(27) LOADW(28) LOADW(29) LOADW(30) LOADW(31)

  float c_reg = 0.0f;
  if (tid < HH) {
    c_reg = c0[b * HH + tid];
    hsh[tid] = __float2half(h0[b * HH + tid]);
  }
  __syncthreads();

  float*       my_out  = xch + ((size_t)(b * 2 + half) * 2) * 512;
  const float* peer_in = xch + ((size_t)(b * 2 + (half ^ 1)) * 2) * 512;
  int* my_flag   = flags + (b * 2 + half);
  int* peer_flag = flags + (b * 2 + (half ^ 1));
  const __half* wxTb = WXT + ((size_t)b * G4 + j) * TT;
  float* outb = out + (size_t)b * HH * TT;

  float4 wxcur = *(const float4*)(wxTb);   // steps 0..7
  for (int t8 = 0; t8 < 64; ++t8) {
    float4 wxnext = *(const float4*)(wxTb + ((size_t)((t8 + 1) & 63) * 8));
#pragma unroll
    for (int u = 0; u < 8; ++u) {
      int t = t8 * 8 + u;
      float fw = (u < 2) ? wxcur.x : (u < 4) ? wxcur.y : (u < 6) ? wxcur.z : wxcur.w;
      half2_t hp = __builtin_bit_cast(half2_t, fw);
      float wx = (float)((u & 1) ? hp.y : hp.x);

      // one b64 LDS read per wave: lane l -> h[4l..4l+3]
      int2 hv = *(const int2*)((const char*)hsh + lane * 8);
      int hA = hv.x;   // h pairs 2*lane
      int hB = hv.y;   // h pair 2*lane+1

      float a0 = 0.f, a1 = 0.f, a2 = 0.f, a3 = 0.f;
      DOTBLK(0)  DOTBLK(1)  DOTBLK(2)  DOTBLK(3)  DOTBLK(4)  DOTBLK(5)
      DOTBLK(6)  DOTBLK(7)  DOTBLK(8)  DOTBLK(9)  DOTBLK(10) DOTBLK(11)
      DOTBLK(12) DOTBLK(13) DOTBLK(14) DOTBLK(15) DOTBLK(16) DOTBLK(17)
      DOTBLK(18) DOTBLK(19) DOTBLK(20) DOTBLK(21) DOTBLK(22) DOTBLK(23)
      DOTBLK(24) DOTBLK(25) DOTBLK(26) DOTBLK(27) DOTBLK(28) DOTBLK(29)
      DOTBLK(30) DOTBLK(31)

      float gate = fast_tanh((a0 + a1) + (a2 + a3) + wx);
      gown[tid] = gate;
      my_out[(t & 1) * 512 + tid] = gate;
      __syncthreads();   // LDS visible + drains the gate stores
      if (tid == 0) {
        __hip_atomic_store(my_flag, t + 1, __ATOMIC_RELEASE, __HIP_MEMORY_SCOPE_AGENT);
        while (__hip_atomic_load(peer_flag, __ATOMIC_ACQUIRE, __HIP_MEMORY_SCOPE_AGENT) < t + 1) {
          __builtin_amdgcn_s_sleep(1);
        }
      }
      __syncthreads();   // all threads held until peer's gates visible
      if (tid < HH) {
        float own_a  = gown[tid];
        float own_b  = gown[HH + tid];
        float peer_a = peer_in[(t & 1) * 512 + tid];
        float peer_b = peer_in[(t & 1) * 512 + HH + tid];
        float ig = half ? peer_a : own_a;
        float fg = half ? peer_b : own_b;
        float gg = half ? own_a  : peer_a;
        float og = half ? own_b  : peer_b;
        c_reg = c_reg * fast_sig(fg) + fast_sig(ig) * fast_tanh(gg);
        float hv2 = fast_sig(og) * fast_tanh(c_reg);
        hsh[tid] = __float2half(hv2);
        if (half == 0) hbuf[t & 15][tid] = hv2;
      }
      __syncthreads();   // h ready for next step; hbuf complete
      if (half == 0 && (t & 15) == 15) {
        int t0v = t - 15;
#pragma unroll
        for (int q = 0; q < 2; ++q) {
          int idx = tid + q * 512;
          int jj  = idx >> 2;
          int s0  = (idx & 3) << 2;
          float4 v;
          v.x = hbuf[s0 + 0][jj];
          v.y = hbuf[s0 + 1][jj];
          v.z = hbuf[s0 + 2][jj];
          v.w = hbuf[s0 + 3][jj];
          *(float4*)(outb + (size_t)jj * TT + t0v + s0) = v;
        }
      }
    }
    wxcur = wxnext;
  }
  if (half == 0 && tid < HH) out[(size_t)BB * HH * TT + b * HH + tid] = c_reg;
}

// ---------------------------------------------------------------------------
extern "C" void kernel_launch(void* const* d_in, const int* in_sizes, int n_in,
                              void* d_out, int out_size, void* d_ws, size_t ws_size,
                              hipStream_t stream) {
  const float* x    = (const float*)d_in[0];
  const float* h0   = (const float*)d_in[1];
  const float* c0   = (const float*)d_in[2];
  const float* W_ih = (const float*)d_in[3];
  const float* W_hh = (const float*)d_in[4];
  const float* b_h  = (const float*)d_in[5];
  float* out = (float*)d_out;

  // Workspace layout:
  //   [0,   32 MB)   Wc   : f16 W_hh transposed, (B,4H,H)
  //   [32,  96 MB)   WXT  : f16 wx+bias, (B,4H,T)  -- t contiguous
  //   [96 MB, +512K) xch  : gate exchange
  //   then           flags: (B,2) int
  char* ws = (char*)d_ws;
  __half* Wc    = (__half*)ws;
  __half* WXT   = (__half*)(ws + (size_t)32 * 1024 * 1024);
  float*  xch   = (float*)(ws + (size_t)96 * 1024 * 1024);
  int*    flags = (int*)(ws + (size_t)96 * 1024 * 1024 + 512 * 1024);

  hipMemsetAsync(flags, 0, BB * 2 * sizeof(int), stream);
  transpose_whh<<<dim3(G4 / 32, HH / 32, BB), dim3(32, 8), 0, stream>>>(W_hh, Wc);
  gemm_wx<<<dim3(G4 / 64, TT / 64, BB), dim3(256), 0, stream>>>(x, W_ih, b_h, WXT);
  lstm_rec5<<<dim3(128), dim3(512), 0, stream>>>(Wc, WXT, h0, c0, out, xch, flags);
}